// Round 2
// baseline (245.124 us; speedup 1.0000x reference)
//
#include <hip/hip_runtime.h>

// Trilinear resample of (B=4, D=64, H=64, W=64, C=32) fp32, identity affine:
// sample coord = p * 62/63 per axis. Each thread produces TWO consecutive-x
// output voxels (one float4 channel-quad each). The pair shares y/z corners
// and overlaps in x: 3 consecutive x-positions per (z,y) corner cover both
// voxels' x0/x1 -> 12 loads per 2 outputs (vs 16), all issued before use
// for max memory-level parallelism. Geometry guarantees p+2 <= 63 (no clamp).

#define C4 8  // float4 quads per voxel (32 ch / 4)

__device__ __forceinline__ void fma4(float4& a, const float4 v, float w) {
    a.x = fmaf(v.x, w, a.x);
    a.y = fmaf(v.y, w, a.y);
    a.z = fmaf(v.z, w, a.z);
    a.w = fmaf(v.w, w, a.w);
}

__global__ __launch_bounds__(256) void trilerp2_kernel(
    const float4* __restrict__ in, float4* __restrict__ out) {
    int t = blockIdx.x * blockDim.x + threadIdx.x;

    int cq = t & (C4 - 1);
    int pv = t >> 3;              // voxel-pair index
    int kp = pv & 31;             // pair within row
    int j  = (pv >> 5) & 63;     // height
    int i  = (pv >> 11) & 63;    // depth
    int b  = pv >> 17;           // batch

    const float s = 62.0f / 63.0f;
    int k0 = kp << 1;
    float xs0 = (float)k0 * s;
    float xs1 = (float)(k0 + 1) * s;
    float ys  = (float)j * s;
    float zs  = (float)i * s;

    int x00 = (int)xs0;           // p
    int x01 = (int)xs1;           // p or p+1
    int y0  = (int)ys;
    int z0  = (int)zs;
    float fx0 = xs0 - (float)x00;
    float fx1 = xs1 - (float)x01;
    float fy  = ys - (float)y0;
    float fz  = zs - (float)z0;
    float gy = 1.0f - fy, gz = 1.0f - fz;

    // shared (z,y) corner weights
    float w00 = gy * gz;   // z0,y0
    float w01 = fy * gz;   // z0,y1
    float w10 = gy * fz;   // z1,y0
    float w11 = fy * fz;   // z1,y1

    // voxel0 x-taps: p (1-fx0), p+1 (fx0), p+2 (0) -> skip tap2
    float a0 = 1.0f - fx0;
    float a1 = fx0;
    // voxel1 x-taps depend on whether x01 advanced past p
    bool adv = x01 > x00;
    float b0 = adv ? 0.0f        : (1.0f - fx1);
    float b1 = adv ? (1.0f - fx1) : fx1;
    float b2 = adv ? fx1         : 0.0f;

    // float4-granular row bases: (((b*64+z)*64+y)*64 + x)*8 + cq
    int bb = b << 21;
    const float4* r00 = in + bb + (z0 << 15)        + (y0 << 9)        + (x00 << 3) + cq;
    const float4* r01 = in + bb + (z0 << 15)        + ((y0 + 1) << 9)  + (x00 << 3) + cq;
    const float4* r10 = in + bb + ((z0 + 1) << 15)  + (y0 << 9)        + (x00 << 3) + cq;
    const float4* r11 = in + bb + ((z0 + 1) << 15)  + ((y0 + 1) << 9)  + (x00 << 3) + cq;

    // 12 loads, all independent, issued before any use
    float4 v00_0 = r00[0], v00_1 = r00[8], v00_2 = r00[16];
    float4 v01_0 = r01[0], v01_1 = r01[8], v01_2 = r01[16];
    float4 v10_0 = r10[0], v10_1 = r10[8], v10_2 = r10[16];
    float4 v11_0 = r11[0], v11_1 = r11[8], v11_2 = r11[16];
    __builtin_amdgcn_sched_barrier(0);

    float4 acc0 = make_float4(0.f, 0.f, 0.f, 0.f);
    float4 acc1 = make_float4(0.f, 0.f, 0.f, 0.f);

    // voxel0: taps 0,1
    fma4(acc0, v00_0, w00 * a0);  fma4(acc0, v00_1, w00 * a1);
    fma4(acc0, v01_0, w01 * a0);  fma4(acc0, v01_1, w01 * a1);
    fma4(acc0, v10_0, w10 * a0);  fma4(acc0, v10_1, w10 * a1);
    fma4(acc0, v11_0, w11 * a0);  fma4(acc0, v11_1, w11 * a1);

    // voxel1: taps 0,1,2
    fma4(acc1, v00_0, w00 * b0);  fma4(acc1, v00_1, w00 * b1);  fma4(acc1, v00_2, w00 * b2);
    fma4(acc1, v01_0, w01 * b0);  fma4(acc1, v01_1, w01 * b1);  fma4(acc1, v01_2, w01 * b2);
    fma4(acc1, v10_0, w10 * b0);  fma4(acc1, v10_1, w10 * b1);  fma4(acc1, v10_2, w10 * b2);
    fma4(acc1, v11_0, w11 * b0);  fma4(acc1, v11_1, w11 * b1);  fma4(acc1, v11_2, w11 * b2);

    // output: vox0 = (((b*64+i)*64+j)*64 + k0), float4 idx = vox*8 + cq
    int o0 = (((((b << 6) + i) << 6) + j) << 6 | k0) * 8 + cq;
    out[o0]     = acc0;
    out[o0 + 8] = acc1;
}

extern "C" void kernel_launch(void* const* d_in, const int* in_sizes, int n_in,
                              void* d_out, int out_size, void* d_ws, size_t ws_size,
                              hipStream_t stream) {
    const float4* in = (const float4*)d_in[0];
    float4* out = (float4*)d_out;

    const int total = 4 * 64 * 64 * 32 * C4;   // 4,194,304 threads (2 outputs each)
    const int block = 256;
    const int grid = total / block;            // 16,384 blocks

    trilerp2_kernel<<<grid, block, 0, stream>>>(in, out);
}

// Round 3
// 240.027 us; speedup vs baseline: 1.0212x; 1.0212x over previous
//
#include <hip/hip_runtime.h>

// Trilinear resample of (B=4, D=64, H=64, W=64, C=32) fp32, identity affine,
// scale s = 62/63. Closed form: floor(q*s) = max(q-1,0), frac weight on
// in[q-1] is exactly q/63. Separable 2-tap blend per axis.
//
// Each thread fixes (b, i=z_out, j=y_out, cq=channel-quad) and walks a chunk
// of 16 x-positions. It streams 4 input rows ((i-1,i) x (j-1,j)), loading ONE
// new float4 per row per step; the x-blend partner comes from the previous
// step's register (C = row-combined value at x=k-1). 4.25 loads/output vs 8
// for the naive gather -> ~2x fewer L1 line transactions (the measured wall).

#define INV63 0.015873015873015872f  // 1/63

__global__ __launch_bounds__(256) void trilerp_walk(
    const float4* __restrict__ in, float4* __restrict__ out) {
    int t = blockIdx.x * blockDim.x + threadIdx.x;

    int cq = t & 7;
    int j  = (t >> 3) & 63;    // output y
    int c  = (t >> 9) & 3;     // x-chunk (16 outputs each)
    int i  = (t >> 11) & 63;   // output z
    int b  = t >> 17;          // batch

    int zl = (i > 0) ? (i - 1) : 0;
    int yl = (j > 0) ? (j - 1) : 0;
    float wzl = (float)i * INV63, wzh = 1.0f - wzl;  // weight on z=i-1 / z=i
    float wyl = (float)j * INV63, wyh = 1.0f - wyl;
    float w00 = wzl * wyl;   // (z=i-1, y=j-1)
    float w01 = wzl * wyh;   // (z=i-1, y=j)
    float w10 = wzh * wyl;   // (z=i,   y=j-1)
    float w11 = wzh * wyh;   // (z=i,   y=j)

    int k0 = c << 4;
    int bb = b << 21;
    // float4 index of row (z,y) at x: bb + z*32768 + y*512 + x*8 + cq
    const float4* r00 = in + bb + (zl << 15) + (yl << 9) + (k0 << 3) + cq;
    const float4* r01 = in + bb + (zl << 15) + (j  << 9) + (k0 << 3) + cq;
    const float4* r10 = in + bb + (i  << 15) + (yl << 9) + (k0 << 3) + cq;
    const float4* r11 = in + bb + (i  << 15) + (j  << 9) + (k0 << 3) + cq;

    // Preload "cur" (x = k0-1). For chunk 0, load x=0; its weight is 0 at k=0.
    int pre = (c == 0) ? 0 : -8;
    float4 c00 = r00[pre], c01 = r01[pre], c10 = r10[pre], c11 = r11[pre];
    float4 C;
    C.x = fmaf(w00, c00.x, fmaf(w01, c01.x, fmaf(w10, c10.x, w11 * c11.x)));
    C.y = fmaf(w00, c00.y, fmaf(w01, c01.y, fmaf(w10, c10.y, w11 * c11.y)));
    C.z = fmaf(w00, c00.z, fmaf(w01, c01.z, fmaf(w10, c10.z, w11 * c11.z)));
    C.w = fmaf(w00, c00.w, fmaf(w01, c01.w, fmaf(w10, c10.w, w11 * c11.w)));

    int vox0 = ((b * 64 + i) * 64 + j) * 64 + k0;
    float4* ob = out + vox0 * 8 + cq;

    float wx0 = (float)k0 * INV63;

#pragma unroll
    for (int u = 0; u < 16; ++u) {
        float4 n00 = r00[u * 8];
        float4 n01 = r01[u * 8];
        float4 n10 = r10[u * 8];
        float4 n11 = r11[u * 8];

        float4 N;
        N.x = fmaf(w00, n00.x, fmaf(w01, n01.x, fmaf(w10, n10.x, w11 * n11.x)));
        N.y = fmaf(w00, n00.y, fmaf(w01, n01.y, fmaf(w10, n10.y, w11 * n11.y)));
        N.z = fmaf(w00, n00.z, fmaf(w01, n01.z, fmaf(w10, n10.z, w11 * n11.z)));
        N.w = fmaf(w00, n00.w, fmaf(w01, n01.w, fmaf(w10, n10.w, w11 * n11.w)));

        // out = wxl*C + (1-wxl)*N  =  N + wxl*(C - N),  wxl = (k0+u)/63
        float wxl = wx0 + (float)u * INV63;
        float4 o;
        o.x = fmaf(wxl, C.x - N.x, N.x);
        o.y = fmaf(wxl, C.y - N.y, N.y);
        o.z = fmaf(wxl, C.z - N.z, N.z);
        o.w = fmaf(wxl, C.w - N.w, N.w);

        ob[u * 8] = o;
        C = N;
    }
}

extern "C" void kernel_launch(void* const* d_in, const int* in_sizes, int n_in,
                              void* d_out, int out_size, void* d_ws, size_t ws_size,
                              hipStream_t stream) {
    const float4* in = (const float4*)d_in[0];
    float4* out = (float4*)d_out;

    // threads = B*D*H*chunks*cq = 4*64*64*4*8 = 524288, 16 outputs each
    const int total = 4 * 64 * 64 * 4 * 8;
    const int block = 256;
    const int grid = total / block;  // 2048 blocks

    trilerp_walk<<<grid, block, 0, stream>>>(in, out);
}